// Round 13
// baseline (213.102 us; speedup 1.0000x reference)
//
#include <hip/hip_runtime.h>
#include <math.h>

// ---------------------------------------------------------------------------
// Deformable-attention decoder layer. bf16 MFMA GEMMs (templated tiles,
// swizzled LDS, 2-phase prefetch); fused GEMM+residual+LayerNorm epilogues;
// direct-fp32 value projection; branchless 2-query/wave sampler.
// N=8, Lq=1024, D=256, NH=8, NL=4, NP=4, DH=32, DFFN=1024
// ---------------------------------------------------------------------------

typedef __bf16 bf16x8 __attribute__((ext_vector_type(8)));
typedef float  f32x4  __attribute__((ext_vector_type(4)));
typedef unsigned short ushort8 __attribute__((ext_vector_type(8)));

#define VB0 0
#define VB1 18874368   // 8*9216*256
#define VB2 23592960   // +8*2304*256
#define VB3 24772608   // +8*576*256
#define VTOT 25067520

__device__ __forceinline__ unsigned short f2bf(float f) {
    unsigned u = __float_as_uint(f);
    u += 0x7FFF + ((u >> 16) & 1);           // RNE
    return (unsigned short)(u >> 16);
}

__device__ __forceinline__ void gload16(const void* g, void* l) {
    __builtin_amdgcn_global_load_lds(
        (const __attribute__((address_space(1))) unsigned int*)g,
        (__attribute__((address_space(3))) unsigned int*)l, 16, 0, 0);
}

// ---------------------------------------------------------------------------
// prep (unchanged from round 11)
// ---------------------------------------------------------------------------
__global__ __launch_bounds__(256) void prep_kernel(
    const float* __restrict__ tgt, const float* __restrict__ Woff,
    const float* __restrict__ Wattn, const float* __restrict__ Wout,
    const float* __restrict__ W1, const float* __restrict__ W2,
    const float* __restrict__ boff, const float* __restrict__ battn,
    const float* __restrict__ Wv0, const float* __restrict__ Wv1,
    unsigned short* __restrict__ tgt_bf, unsigned short* __restrict__ Btoa,
    unsigned short* __restrict__ WoT, unsigned short* __restrict__ W1T,
    unsigned short* __restrict__ W2T, float* __restrict__ boa,
    unsigned short* __restrict__ WvT0, unsigned short* __restrict__ WvT1)
{
    __shared__ float sT[64][65];
    const int b = blockIdx.x, t = threadIdx.x;
    if (b < 2048) {
        const int i = (b * 256 + t) * 4;
        const float4 v = *(const float4*)&tgt[i];
        ushort4 o;
        o.x = f2bf(v.x); o.y = f2bf(v.y); o.z = f2bf(v.z); o.w = f2bf(v.w);
        *(ushort4*)&tgt_bf[i] = o;
        return;
    }
    if (b == 2048) {
        if (t < 384) boa[t] = (t < 256) ? boff[t] : battn[t - 256];
#pragma unroll
        for (int k = 0; k < 16; ++k) {
            WvT0[t * 32 + k]      = f2bf(Wv0[k * 256 + t]);
            WvT0[t * 32 + 16 + k] = 0;
        }
#pragma unroll
        for (int k = 0; k < 32; ++k)
            WvT1[t * 32 + k] = f2bf(Wv1[k * 256 + t]);
        return;
    }
    int tb = b - 2049;
    const float* src; unsigned short* dst; int srcN, dstK, tn, tk;
    if (tb < 16)       { src = Woff;  dst = Btoa;          srcN = 256;  dstK = 256;  tn = tb >> 2; tk = tb & 3; }
    else if (tb < 24)  { tb -= 16; src = Wattn; dst = Btoa + 65536; srcN = 128; dstK = 256; tn = tb >> 2; tk = tb & 3; }
    else if (tb < 40)  { tb -= 24; src = Wout;  dst = WoT; srcN = 256;  dstK = 256;  tn = tb >> 2; tk = tb & 3; }
    else if (tb < 104) { tb -= 40; src = W1;    dst = W1T; srcN = 1024; dstK = 256;  tn = tb >> 2; tk = tb & 3; }
    else               { tb -= 104; src = W2;   dst = W2T; srcN = 256;  dstK = 1024; tn = tb >> 4; tk = tb & 15; }
    const int n0 = tn * 64, k0 = tk * 64;
    const int j = t & 63, i0 = t >> 6;
#pragma unroll
    for (int s = 0; s < 16; ++s) {
        const int i = i0 + s * 4;
        sT[i][j] = src[(size_t)(k0 + i) * srcN + n0 + j];
    }
    __syncthreads();
#pragma unroll
    for (int s = 0; s < 16; ++s) {
        const int nr = i0 + s * 4;
        dst[(size_t)(n0 + nr) * dstK + k0 + j] = f2bf(sT[j][nr]);
    }
}

// ---------------------------------------------------------------------------
// bf16 MFMA GEMM, templated tile (unchanged)
// ---------------------------------------------------------------------------
template <int BM, int BN, int RELU, int OUTBF16>
__global__ __launch_bounds__(256) void gemm_bf16(
    const unsigned short* __restrict__ A, const unsigned short* __restrict__ Bt,
    const float* __restrict__ bias, float* __restrict__ C32,
    unsigned short* __restrict__ C16, int M, int N, int K)
{
    constexpr int MF = BM / 32, NF = BN / 32;
    constexpr int CA = BM / 16, CB = BN / 16;
    constexpr int CPW = (CA + CB) / 4;

    __shared__ unsigned short As[2][BM * 32];
    __shared__ unsigned short Bs[2][BN * 32];

    const int t = threadIdx.x, wv = t >> 6, l = t & 63;
    const int m0 = blockIdx.y * BM, n0 = blockIdx.x * BN;
    const int wm = wv >> 1, wn = wv & 1;
    const int lr = l >> 2, sl = l & 3;
    const int swsl = sl ^ ((lr >> 1) & 3);
    const int fr = l & 15, kg = l >> 4;
    const int rsw = (fr >> 1) & 3;

    f32x4 acc[MF][NF];
#pragma unroll
    for (int i = 0; i < MF; ++i)
#pragma unroll
        for (int j = 0; j < NF; ++j) acc[i][j] = (f32x4){0.f, 0.f, 0.f, 0.f};

#define STAGE(bufi, k0)                                                        \
    do {                                                                       \
        _Pragma("unroll")                                                      \
        for (int cc = 0; cc < CPW; ++cc) {                                     \
            const int ch = wv * CPW + cc;                                      \
            if (ch < CA) {                                                     \
                gload16(A + (size_t)(m0 + ch * 16 + lr) * K + (k0) + swsl * 8, \
                        &As[bufi][ch * 512]);                                  \
            } else {                                                           \
                const int cb2 = ch - CA;                                       \
                gload16(Bt + (size_t)(n0 + cb2 * 16 + lr) * K + (k0) + swsl * 8,\
                        &Bs[bufi][cb2 * 512]);                                 \
            }                                                                  \
        }                                                                      \
    } while (0)

    const int NT = K >> 5;
    STAGE(0, 0);
    asm volatile("s_waitcnt vmcnt(0)" ::: "memory");
    __syncthreads();

    for (int tt = 0; tt < NT; ++tt) {
        const int cur = tt & 1;
        if (tt + 1 < NT) STAGE(cur ^ 1, (tt + 1) * 32);

        bf16x8 af[MF], bfr[NF];
#pragma unroll
        for (int i = 0; i < MF; ++i)
            af[i] = *(const bf16x8*)&As[cur][(wm * (MF * 16) + i * 16 + fr) * 32 + (kg ^ rsw) * 8];
#pragma unroll
        for (int j = 0; j < NF; ++j)
            bfr[j] = *(const bf16x8*)&Bs[cur][(wn * (NF * 16) + j * 16 + fr) * 32 + (kg ^ rsw) * 8];
#pragma unroll
        for (int i = 0; i < MF; ++i)
#pragma unroll
            for (int j = 0; j < NF; ++j)
                acc[i][j] = __builtin_amdgcn_mfma_f32_16x16x32_bf16(af[i], bfr[j], acc[i][j], 0, 0, 0);

        asm volatile("s_waitcnt vmcnt(0)" ::: "memory");
        __syncthreads();
    }
#undef STAGE

    const int q4 = (l >> 4) * 4;
#pragma unroll
    for (int j = 0; j < NF; ++j) {
        const int col = n0 + wn * (NF * 16) + j * 16 + fr;
        const float bj = bias[col];
#pragma unroll
        for (int i = 0; i < MF; ++i) {
#pragma unroll
            for (int r = 0; r < 4; ++r) {
                const int row = m0 + wm * (MF * 16) + i * 16 + q4 + r;
                float v = acc[i][j][r] + bj;
                if (RELU) v = fmaxf(v, 0.f);
                if (OUTBF16) C16[(size_t)row * N + col] = f2bf(v);
                else         C32[(size_t)row * N + col] = v;
            }
        }
    }
}

// ---------------------------------------------------------------------------
// FUSED GEMM + residual + LayerNorm. N fixed at 256 (full row per block).
// BM=32, 4 waves side-by-side (wave wn covers rows 0..31 x cols wn*64..+63).
// Epilogue: v = acc + bias + resid; row-LN via shfl(fr-group) + LDS cross-wave.
// out32 = LN(v)*g + be;  optional bf16 copy.
// ---------------------------------------------------------------------------
template <int OUT16>
__global__ __launch_bounds__(256) void gemm_ln(
    const unsigned short* __restrict__ A, const unsigned short* __restrict__ Bt,
    const float* __restrict__ bias, const float* __restrict__ resid,
    const float* __restrict__ g, const float* __restrict__ be,
    float* __restrict__ out32, unsigned short* __restrict__ out16,
    int M, int K)
{
    __shared__ unsigned short As[2][32 * 32];
    __shared__ unsigned short Bs[2][256 * 32];
    __shared__ float sLN[4][32][2];

    const int t = threadIdx.x, wv = t >> 6, l = t & 63;
    const int m0 = blockIdx.x * 32;
    const int wn = wv;
    const int lr = l >> 2, sl = l & 3;
    const int swsl = sl ^ ((lr >> 1) & 3);
    const int fr = l & 15, kg = l >> 4;
    const int rsw = (fr >> 1) & 3;

    f32x4 acc[2][4];
#pragma unroll
    for (int i = 0; i < 2; ++i)
#pragma unroll
        for (int j = 0; j < 4; ++j) acc[i][j] = (f32x4){0.f, 0.f, 0.f, 0.f};

    // 18 staging chunks: 0,1 = A (16 rows each); 2..17 = B chunk-2.
#define STAGE_LN(bufi, k0)                                                     \
    for (int ch = wv; ch < 18; ch += 4) {                                      \
        if (ch < 2) {                                                          \
            gload16(A + (size_t)(m0 + ch * 16 + lr) * K + (k0) + swsl * 8,     \
                    &As[bufi][ch * 512]);                                      \
        } else {                                                               \
            gload16(Bt + (size_t)((ch - 2) * 16 + lr) * K + (k0) + swsl * 8,   \
                    &Bs[bufi][(ch - 2) * 512]);                                \
        }                                                                      \
    }

    const int NT = K >> 5;
    STAGE_LN(0, 0);
    asm volatile("s_waitcnt vmcnt(0)" ::: "memory");
    __syncthreads();

    for (int tt = 0; tt < NT; ++tt) {
        const int cur = tt & 1;
        if (tt + 1 < NT) { STAGE_LN(cur ^ 1, (tt + 1) * 32); }

        bf16x8 af[2], bfr[4];
#pragma unroll
        for (int i = 0; i < 2; ++i)
            af[i] = *(const bf16x8*)&As[cur][(i * 16 + fr) * 32 + (kg ^ rsw) * 8];
#pragma unroll
        for (int j = 0; j < 4; ++j)
            bfr[j] = *(const bf16x8*)&Bs[cur][(wn * 64 + j * 16 + fr) * 32 + (kg ^ rsw) * 8];
#pragma unroll
        for (int i = 0; i < 2; ++i)
#pragma unroll
            for (int j = 0; j < 4; ++j)
                acc[i][j] = __builtin_amdgcn_mfma_f32_16x16x32_bf16(af[i], bfr[j], acc[i][j], 0, 0, 0);

        asm volatile("s_waitcnt vmcnt(0)" ::: "memory");
        __syncthreads();
    }
#undef STAGE_LN

    const int q4 = kg * 4;
    float bj[4];
#pragma unroll
    for (int j = 0; j < 4; ++j) bj[j] = bias[wn * 64 + j * 16 + fr];

    // v = acc + bias + resid; accumulate row partials
    float s[2][4] = {}, q[2][4] = {};
#pragma unroll
    for (int i = 0; i < 2; ++i)
#pragma unroll
        for (int r = 0; r < 4; ++r) {
            const int row = m0 + i * 16 + q4 + r;
#pragma unroll
            for (int j = 0; j < 4; ++j) {
                const int col = wn * 64 + j * 16 + fr;
                float v = acc[i][j][r] + bj[j] + resid[(size_t)row * 256 + col];
                acc[i][j][r] = v;
                s[i][r] += v;
                q[i][r] += v * v;
            }
        }
    // reduce over the 16-lane fr group
#pragma unroll
    for (int o = 1; o < 16; o <<= 1) {
#pragma unroll
        for (int i = 0; i < 2; ++i)
#pragma unroll
            for (int r = 0; r < 4; ++r) {
                s[i][r] += __shfl_xor(s[i][r], o);
                q[i][r] += __shfl_xor(q[i][r], o);
            }
    }
    if (fr == 0) {
#pragma unroll
        for (int i = 0; i < 2; ++i)
#pragma unroll
            for (int r = 0; r < 4; ++r) {
                sLN[wn][i * 16 + q4 + r][0] = s[i][r];
                sLN[wn][i * 16 + q4 + r][1] = q[i][r];
            }
    }
    __syncthreads();

#pragma unroll
    for (int i = 0; i < 2; ++i)
#pragma unroll
        for (int r = 0; r < 4; ++r) {
            const int rloc = i * 16 + q4 + r;
            const float S = sLN[0][rloc][0] + sLN[1][rloc][0] + sLN[2][rloc][0] + sLN[3][rloc][0];
            const float Q = sLN[0][rloc][1] + sLN[1][rloc][1] + sLN[2][rloc][1] + sLN[3][rloc][1];
            const float mean = S * (1.f / 256.f);
            const float rstd = rsqrtf(Q * (1.f / 256.f) - mean * mean + 1e-5f);
            const int row = m0 + rloc;
#pragma unroll
            for (int j = 0; j < 4; ++j) {
                const int col = wn * 64 + j * 16 + fr;
                const float y = (acc[i][j][r] - mean) * rstd * g[col] + be[col];
                out32[(size_t)row * 256 + col] = y;
                if (OUT16) out16[(size_t)row * 256 + col] = f2bf(y);
            }
        }
}

// ---------------------------------------------------------------------------
// value projection (unchanged from round 11)
// ---------------------------------------------------------------------------
__global__ __launch_bounds__(256) void vproj_gemm(
    const float* __restrict__ src0, const float* __restrict__ src1,
    const float* __restrict__ src2, const float* __restrict__ src3,
    const unsigned short* __restrict__ WvT0, const unsigned short* __restrict__ WvT1,
    const float* __restrict__ bv0, const float* __restrict__ bv1,
    unsigned short* __restrict__ vals)
{
    __shared__ unsigned short As[128 * 32];
    __shared__ unsigned short Bs[128 * 32];

    const int ly = blockIdx.y;
    const float* A32; const unsigned short* Bt; const float* bias;
    size_t ob; int lm, Kr;
    if (ly < 576)      { A32 = src0; Bt = WvT0; bias = bv0; ob = VB0; lm = ly;       Kr = 16; }
    else if (ly < 720) { A32 = src1; Bt = WvT1; bias = bv1; ob = VB1; lm = ly - 576; Kr = 32; }
    else if (ly < 756) { A32 = src2; Bt = WvT0; bias = bv0; ob = VB2; lm = ly - 720; Kr = 16; }
    else               { A32 = src3; Bt = WvT1; bias = bv1; ob = VB3; lm = ly - 756; Kr = 32; }

    const int t = threadIdx.x, wv = t >> 6, l = t & 63;
    const int m0 = lm * 128, n0 = blockIdx.x * 128;
    const int wm = wv >> 1, wn = wv & 1;
    const int lr = l >> 2, sl = l & 3;
    const int swsl = sl ^ ((lr >> 1) & 3);
    const int fr = l & 15, kg = l >> 4;
    const int rsw = (fr >> 1) & 3;

#pragma unroll
    for (int cc = 0; cc < 2; ++cc) {
        const int ch = wv * 2 + cc;
        gload16(Bt + (size_t)(n0 + ch * 16 + lr) * 32 + swsl * 8, &Bs[ch * 512]);
    }
    {
        const int r = t >> 1, hh = t & 1;
        const int rs = (r >> 1) & 3;
        if (Kr == 32) {
            const float4* sp = (const float4*)(A32 + (size_t)(m0 + r) * 32 + hh * 16);
            const float4 a0 = sp[0], a1 = sp[1], a2 = sp[2], a3 = sp[3];
            ushort8 w0, w1;
            w0[0] = f2bf(a0.x); w0[1] = f2bf(a0.y); w0[2] = f2bf(a0.z); w0[3] = f2bf(a0.w);
            w0[4] = f2bf(a1.x); w0[5] = f2bf(a1.y); w0[6] = f2bf(a1.z); w0[7] = f2bf(a1.w);
            w1[0] = f2bf(a2.x); w1[1] = f2bf(a2.y); w1[2] = f2bf(a2.z); w1[3] = f2bf(a2.w);
            w1[4] = f2bf(a3.x); w1[5] = f2bf(a3.y); w1[6] = f2bf(a3.z); w1[7] = f2bf(a3.w);
            *(ushort8*)&As[r * 32 + ((hh * 2 + 0) ^ rs) * 8] = w0;
            *(ushort8*)&As[r * 32 + ((hh * 2 + 1) ^ rs) * 8] = w1;
        } else {
            if (hh == 0) {
                const float4* sp = (const float4*)(A32 + (size_t)(m0 + r) * 16);
                const float4 a0 = sp[0], a1 = sp[1], a2 = sp[2], a3 = sp[3];
                ushort8 w0, w1;
                w0[0] = f2bf(a0.x); w0[1] = f2bf(a0.y); w0[2] = f2bf(a0.z); w0[3] = f2bf(a0.w);
                w0[4] = f2bf(a1.x); w0[5] = f2bf(a1.y); w0[6] = f2bf(a1.z); w0[7] = f2bf(a1.w);
                w1[0] = f2bf(a2.x); w1[1] = f2bf(a2.y); w1[2] = f2bf(a2.z); w1[3] = f2bf(a2.w);
                w1[4] = f2bf(a3.x); w1[5] = f2bf(a3.y); w1[6] = f2bf(a3.z); w1[7] = f2bf(a3.w);
                *(ushort8*)&As[r * 32 + ((0) ^ rs) * 8] = w0;
                *(ushort8*)&As[r * 32 + ((1) ^ rs) * 8] = w1;
            } else {
                const ushort8 z = {0, 0, 0, 0, 0, 0, 0, 0};
                *(ushort8*)&As[r * 32 + ((2) ^ rs) * 8] = z;
                *(ushort8*)&As[r * 32 + ((3) ^ rs) * 8] = z;
            }
        }
    }
    asm volatile("s_waitcnt vmcnt(0)" ::: "memory");
    __syncthreads();

    f32x4 acc[4][4];
#pragma unroll
    for (int i = 0; i < 4; ++i)
#pragma unroll
        for (int j = 0; j < 4; ++j) acc[i][j] = (f32x4){0.f, 0.f, 0.f, 0.f};

    bf16x8 af[4], bfr[4];
#pragma unroll
    for (int i = 0; i < 4; ++i)
        af[i] = *(const bf16x8*)&As[(wm * 64 + i * 16 + fr) * 32 + (kg ^ rsw) * 8];
#pragma unroll
    for (int j = 0; j < 4; ++j)
        bfr[j] = *(const bf16x8*)&Bs[(wn * 64 + j * 16 + fr) * 32 + (kg ^ rsw) * 8];
#pragma unroll
    for (int i = 0; i < 4; ++i)
#pragma unroll
        for (int j = 0; j < 4; ++j)
            acc[i][j] = __builtin_amdgcn_mfma_f32_16x16x32_bf16(af[i], bfr[j], acc[i][j], 0, 0, 0);

    const int q4 = (l >> 4) * 4;
#pragma unroll
    for (int j = 0; j < 4; ++j) {
        const int col = n0 + wn * 64 + j * 16 + fr;
        const float bj = bias[col];
#pragma unroll
        for (int i = 0; i < 4; ++i) {
#pragma unroll
            for (int r = 0; r < 4; ++r) {
                const int row = m0 + wm * 64 + i * 16 + q4 + r;
                vals[ob + (size_t)row * 256 + col] = f2bf(acc[i][j][r] + bj);
            }
        }
    }
}

// ---------------------------------------------------------------------------
// sampler (unchanged)
// ---------------------------------------------------------------------------
__device__ __forceinline__ void acc8(const unsigned short* p, float w, float* a)
{
    const uint4 u = *(const uint4*)p;
    a[0] = fmaf(w, __uint_as_float(u.x << 16), a[0]);
    a[1] = fmaf(w, __uint_as_float(u.x & 0xffff0000u), a[1]);
    a[2] = fmaf(w, __uint_as_float(u.y << 16), a[2]);
    a[3] = fmaf(w, __uint_as_float(u.y & 0xffff0000u), a[3]);
    a[4] = fmaf(w, __uint_as_float(u.z << 16), a[4]);
    a[5] = fmaf(w, __uint_as_float(u.z & 0xffff0000u), a[5]);
    a[6] = fmaf(w, __uint_as_float(u.w << 16), a[6]);
    a[7] = fmaf(w, __uint_as_float(u.w & 0xffff0000u), a[7]);
}

__global__ __launch_bounds__(256) void sampler_kernel(
    const unsigned short* __restrict__ vals, const float* __restrict__ offlog,
    const float* __restrict__ ref, unsigned short* __restrict__ msout)
{
    __shared__ float sOff[8][256];
    __shared__ float sLog[8][128];
    __shared__ float sRef[8][8];

    const int t = threadIdx.x, w = t >> 6, l = t & 63;
    const int qbase = blockIdx.x * 8;

    for (int j = l; j < 768; j += 64) {
        const int second = (j >= 384);
        const int lq = w * 2 + second;
        const int jj = second ? j - 384 : j;      // 384 is not pow2: no masking
        const float v = offlog[(size_t)(qbase + lq) * 384 + jj];
        if (jj < 256) {
            const int h = jj >> 5, r = jj & 31;
            sOff[lq][(r >> 1) * 16 + h * 2 + (r & 1)] = v;
        } else {
            const int j2 = jj - 256;
            sLog[lq][(j2 & 15) * 8 + (j2 >> 4)] = v;
        }
    }
    if (l < 16)
        sRef[w * 2 + (l >> 3)][l & 7] = ref[(size_t)(qbase + w * 2 + (l >> 3)) * 8 + (l & 7)];
    __syncthreads();

    const int lq = w * 2 + (l >> 5);
    const int b  = qbase + lq;
    const int n  = b >> 10;
    const int h  = (l >> 2) & 7;
    const int lg = l & 3;

    float mx = -1e30f;
#pragma unroll
    for (int i = 0; i < 16; ++i) mx = fmaxf(mx, sLog[lq][i * 8 + h]);
    float e[16], s = 0.f;
#pragma unroll
    for (int i = 0; i < 16; ++i) { e[i] = __expf(sLog[lq][i * 8 + h] - mx); s += e[i]; }
    const float inv = 1.f / s;

    float acc[8] = {0.f, 0.f, 0.f, 0.f, 0.f, 0.f, 0.f, 0.f};
    const int dims[4] = {96, 48, 24, 12};
    const int hwsz[4] = {9216, 2304, 576, 144};
    const size_t vbase[4] = {VB0, VB1, VB2, VB3};

#pragma unroll
    for (int lv = 0; lv < 4; ++lv) {
        const int W = dims[lv];
        const float fx = sRef[lq][lv * 2]     * (float)W - 0.5f;
        const float fy = sRef[lq][lv * 2 + 1] * (float)W - 0.5f;
        const unsigned short* vb =
            vals + vbase[lv] + (size_t)n * hwsz[lv] * 256 + h * 32 + lg * 8;
#pragma unroll
        for (int p = 0; p < 4; ++p) {
            const float2 xy = *(const float2*)&sOff[lq][((lv * 4 + p) * 8 + h) * 2];
            const float x = fx + xy.x;
            const float y = fy + xy.y;
            const float x0f = floorf(x), y0f = floorf(y);
            const float wx = x - x0f, wy = y - y0f;
            const int x0 = (int)x0f, y0 = (int)y0f;
            const float aw = e[lv * 4 + p] * inv;
            const float vx0 = ((unsigned)x0       < (unsigned)W) ? 1.f - wx : 0.f;
            const float vx1 = ((unsigned)(x0 + 1) < (unsigned)W) ? wx       : 0.f;
            const float vy0 = ((unsigned)y0       < (unsigned)W) ? 1.f - wy : 0.f;
            const float vy1 = ((unsigned)(y0 + 1) < (unsigned)W) ? wy       : 0.f;
            const int cx0 = min(max(x0, 0), W - 1);
            const int cx1 = min(max(x0 + 1, 0), W - 1);
            const int cy0 = min(max(y0, 0), W - 1) * W;
            const int cy1 = min(max(y0 + 1, 0), W - 1) * W;
            acc8(vb + (size_t)(cy0 + cx0) * 256, aw * vy0 * vx0, acc);
            acc8(vb + (size_t)(cy0 + cx1) * 256, aw * vy0 * vx1, acc);
            acc8(vb + (size_t)(cy1 + cx0) * 256, aw * vy1 * vx0, acc);
            acc8(vb + (size_t)(cy1 + cx1) * 256, aw * vy1 * vx1, acc);
        }
    }
    uint4 o;
    o.x = (unsigned)f2bf(acc[0]) | ((unsigned)f2bf(acc[1]) << 16);
    o.y = (unsigned)f2bf(acc[2]) | ((unsigned)f2bf(acc[3]) << 16);
    o.z = (unsigned)f2bf(acc[4]) | ((unsigned)f2bf(acc[5]) << 16);
    o.w = (unsigned)f2bf(acc[6]) | ((unsigned)f2bf(acc[7]) << 16);
    *(uint4*)&msout[(size_t)b * 256 + h * 32 + lg * 8] = o;
}

// ---------------------------------------------------------------------------
extern "C" void kernel_launch(void* const* d_in, const int* in_sizes, int n_in,
                              void* d_out, int out_size, void* d_ws, size_t ws_size,
                              hipStream_t stream)
{
    const float* tgt   = (const float*)d_in[0];
    const float* ref   = (const float*)d_in[1];
    const float* src0  = (const float*)d_in[2];
    const float* src1  = (const float*)d_in[3];
    const float* src2  = (const float*)d_in[4];
    const float* src3  = (const float*)d_in[5];
    const float* Wv0   = (const float*)d_in[6];
    const float* bv0   = (const float*)d_in[7];
    const float* Wv1   = (const float*)d_in[8];
    const float* bv1   = (const float*)d_in[9];
    const float* Woff  = (const float*)d_in[10];
    const float* boff  = (const float*)d_in[11];
    const float* Wattn = (const float*)d_in[12];
    const float* battn = (const float*)d_in[13];
    const float* Wout  = (const float*)d_in[14];
    const float* bout  = (const float*)d_in[15];
    const float* g1    = (const float*)d_in[16];
    const float* be1   = (const float*)d_in[17];
    const float* W1    = (const float*)d_in[18];
    const float* b1    = (const float*)d_in[19];
    const float* W2    = (const float*)d_in[20];
    const float* b2    = (const float*)d_in[21];
    const float* g3    = (const float*)d_in[22];
    const float* be3   = (const float*)d_in[23];

    char* w8 = (char*)d_ws;
    unsigned short* vals_bf  = (unsigned short*)(w8 + 0);
    unsigned short* tgt_bf   = (unsigned short*)(w8 + 50135040);
    unsigned short* Btoa     = (unsigned short*)(w8 + 54329344);
    unsigned short* WoT      = (unsigned short*)(w8 + 54525952);
    unsigned short* W1T      = (unsigned short*)(w8 + 54657024);
    unsigned short* W2T      = (unsigned short*)(w8 + 55181312);
    unsigned short* ffn1_bf  = (unsigned short*)(w8 + 55705600);
    unsigned short* msout_bf = (unsigned short*)(w8 + 72482816);
    unsigned short* tbuf16   = (unsigned short*)(w8 + 76677120);
    float* boa    = (float*)(w8 + 80871424);
    float* offlog = (float*)(w8 + 80872960);
    float* tbuf32 = (float*)(w8 + 101844480);
    // WvT staging (region formerly ms2; free until nothing else uses it now)
    unsigned short* WvT0  = (unsigned short*)(w8 + 93455872 + 6266880);  // 16,384 B
    unsigned short* WvT1  = (unsigned short*)(w8 + 93455872 + 6283264);  // 16,384 B

    const dim3 blk(256);

    prep_kernel<<<2217, blk, 0, stream>>>(tgt, Woff, Wattn, Wout, W1, W2, boff, battn,
                                          Wv0, Wv1,
                                          tgt_bf, Btoa, WoT, W1T, W2T, boa, WvT0, WvT1);

    // value projection: single dispatch, all levels, direct fp32 A-staging
    vproj_gemm<<<dim3(2, 765), blk, 0, stream>>>(src0, src1, src2, src3,
                                                 WvT0, WvT1, bv0, bv1, vals_bf);

    // offlog = tgt @ [Woff|Wattn] + [boff|battn]   (8192 x 384, K=256)
    gemm_bf16<64, 128, 0, 0><<<dim3(3, 128), blk, 0, stream>>>(
        tgt_bf, Btoa, boa, offlog, (unsigned short*)nullptr, 8192, 384, 256);
    sampler_kernel<<<1024, blk, 0, stream>>>(vals_bf, offlog, ref, msout_bf);

    // t = LN(tgt + msout @ Wout + bout)  -> tbuf32 + tbuf16   (fused, 256 blocks)
    gemm_ln<1><<<256, blk, 0, stream>>>(msout_bf, WoT, bout, tgt, g1, be1,
                                        tbuf32, tbuf16, 8192, 256);

    // ffn1 = relu(t @ W1 + b1) -> bf16  (512 blocks)
    gemm_bf16<128, 128, 1, 1><<<dim3(8, 64), blk, 0, stream>>>(
        tbuf16, W1T, b1, (float*)nullptr, ffn1_bf, 8192, 1024, 256);

    // out = LN(t + ffn1 @ W2 + b2) -> d_out   (fused, 256 blocks)
    gemm_ln<0><<<256, blk, 0, stream>>>(ffn1_bf, W2T, b2, tbuf32, g3, be3,
                                        (float*)d_out, (unsigned short*)nullptr, 8192, 1024);
}